// Round 4
// baseline (313.558 us; speedup 1.0000x reference)
//
#include <hip/hip_runtime.h>
#include <stdint.h>

#define BATCH 4
#define NPTS 4096
#define KNN 11            // K+1 neighbors including self
#define NPART 8           // partitions per query
#define PART (NPTS / NPART)   // 512
#define QPB 32            // queries per block (256 threads / 8 lanes each)

// monotone float -> uint mapping (ascending): neg flips all bits, pos sets sign bit
__device__ __forceinline__ unsigned sortable_f32(float d) {
    unsigned b = __float_as_uint(d);
    unsigned m = (unsigned)(((int)b) >> 31) | 0x80000000u;
    return b ^ m;
}

__device__ __forceinline__ unsigned long long shfl_xor_u64_w8(unsigned long long v, int mask) {
    unsigned lo = (unsigned)__shfl_xor((int)(unsigned)(v & 0xFFFFFFFFull), mask, 8);
    unsigned hi = (unsigned)__shfl_xor((int)(unsigned)(v >> 32), mask, 8);
    return ((unsigned long long)hi << 32) | lo;
}

// Kernel 1: exact 11-NN per point, replicating the reference's arithmetic:
//   sq_j = fl(fl(x2)+fl(y2)) + fl(z2)            (elementwise square, seq sum, no fma)
//   dot  = fma(z,z', fma(y,y', fl(x*x')))        (BLAS/Eigen K-loop: forward FMA chain)
//   d2   = fl( fl(sq_i+sq_j) - fl(2*dot) )       (no contraction)
// top-k: ascending d2, ties -> LOWER index (stable, lax.top_k semantics).
// Key = (sortable_f32(d2) << 32) | j  : u64 ascending == (d2 asc, j asc on ties).
__global__ __launch_bounds__(256) void knn_kernel(
    const float* __restrict__ pos, int* __restrict__ nn_out)
{
#pragma clang fp contract(off)
    // skewed float4 (x,y,z,sq): index j + (j>>9) so the 8 partition streams
    // start 16B apart instead of aliasing the same banks
    __shared__ float4 sp[NPTS + NPART];

    int b    = blockIdx.x / (NPTS / QPB);   // 128 blocks per batch
    int qblk = blockIdx.x % (NPTS / QPB);
    const float* pb = pos + (size_t)b * NPTS * 3;

    for (int j = threadIdx.x; j < NPTS; j += 256) {
        float x = pb[3*j], y = pb[3*j+1], z = pb[3*j+2];
        float sq = x*x + y*y + z*z;          // contract(off): np sum order
        sp[j + (j >> 9)] = make_float4(x, y, z, sq);
    }
    __syncthreads();

    int q = threadIdx.x >> 3;   // query within block (0..31)
    int p = threadIdx.x & 7;    // partition lane (0..7)
    int i = qblk * QPB + q;     // query index within batch
    float4 qp = sp[i + (i >> 9)];

    // per-lane sorted top-11 of this lane's 512-candidate partition
    unsigned long long kd[KNN];
#pragma unroll
    for (int k = 0; k < KNN; ++k) kd[k] = 0xFFFFFFFFFFFFFFFFull;

    int jbase = p * PART;
    int sbase = p * (PART + 1);             // skewed base for this partition
    for (int jl = 0; jl < PART; ++jl) {
        float4 c = sp[sbase + jl];
        float t  = qp.x * c.x;               // fl(x*x') == fma(x,x',0)
        t = fmaf(qp.y, c.y, t);              // forward FMA chain (BLAS k-loop)
        t = fmaf(qp.z, c.z, t);
        float d2 = (qp.w + c.w) - 2.0f * t;  // fl(si+sj) - fl(2t), unfused
        unsigned long long key =
            ((unsigned long long)sortable_f32(d2) << 32)
            | (unsigned long long)(unsigned)(jbase + jl);
        if (key < kd[KNN-1]) {               // ties: lower j = smaller key wins
            kd[KNN-1] = key;
#pragma unroll
            for (int k = KNN-1; k > 0; --k) {
                if (kd[k] < kd[k-1]) {
                    unsigned long long tu = kd[k]; kd[k] = kd[k-1]; kd[k-1] = tu;
                }
            }
        }
    }

    // merge the 8 sorted lists of each query group (lanes q*8..q*8+7):
    // 11 rounds of group-min over the u64 keys (tie-break baked into key)
    unsigned res[KNN];
#pragma unroll
    for (int r = 0; r < KNN; ++r) {
        unsigned long long h = kd[0], o;
        o = shfl_xor_u64_w8(h, 1); if (o < h) h = o;
        o = shfl_xor_u64_w8(h, 2); if (o < h) h = o;
        o = shfl_xor_u64_w8(h, 4); if (o < h) h = o;
        res[r] = (unsigned)(h & 0xFFFFFFFFull);
        bool own = (kd[0] == h);            // keys unique -> exactly one owner
#pragma unroll
        for (int t = 0; t < KNN-1; ++t) kd[t] = own ? kd[t+1] : kd[t];
        kd[KNN-1] = own ? 0xFFFFFFFFFFFFFFFFull : kd[KNN-1];
    }

    if (p == 0) {
        int* op = nn_out + ((size_t)b * NPTS + (size_t)i) * 12;  // stride 12
#pragma unroll
        for (int r = 0; r < KNN; ++r) op[r] = (int)res[r];
    }
}

// Kernel 2: gather 66 features + 3 unrolled linear layers. One thread per point.
// Weight indices are wave-uniform -> scalar (s_load) weight traffic.
__global__ __launch_bounds__(256) void mlp_kernel(
    const float* __restrict__ pos, const float* __restrict__ vel,
    const float* __restrict__ initc,
    const float* __restrict__ W1, const float* __restrict__ b1,
    const float* __restrict__ W2, const float* __restrict__ b2,
    const float* __restrict__ W3, const float* __restrict__ b3,
    const int* __restrict__ nn, float* __restrict__ out)
{
    int t = blockIdx.x * 256 + threadIdx.x;  // 0..16383
    int b = t >> 12;
    int i = t & (NPTS - 1);

    const int* my_nn = nn + (size_t)t * 12;
    int idx[KNN];
#pragma unroll
    for (int k = 0; k < KNN; ++k) idx[k] = my_nn[k];

    const float* pb = pos + (size_t)b * NPTS * 3;
    const float* vb = vel + (size_t)b * NPTS * 3;
    float px = pb[3*i], py = pb[3*i+1], pz = pb[3*i+2];

    float f[66];
#pragma unroll
    for (int k = 1; k < KNN; ++k) {          // relative positions, ranks 1..10
        const float* pn = pb + 3*idx[k];
        f[3*(k-1)+0] = pn[0] - px;
        f[3*(k-1)+1] = pn[1] - py;
        f[3*(k-1)+2] = pn[2] - pz;
    }
#pragma unroll
    for (int k = 0; k < KNN; ++k) {          // velocities, ranks 0..10 (incl self)
        const float* vn = vb + 3*idx[k];
        f[30+3*k+0] = vn[0];
        f[30+3*k+1] = vn[1];
        f[30+3*k+2] = vn[2];
    }
    f[63] = initc[b*3+0]; f[64] = initc[b*3+1]; f[65] = initc[b*3+2];

    float h1[32];
#pragma unroll
    for (int o = 0; o < 32; ++o) {
        float acc = b1[o];
#pragma unroll
        for (int ff = 0; ff < 66; ++ff) acc = fmaf(f[ff], W1[o*66+ff], acc);
        h1[o] = acc;
    }
    float h2[16];
#pragma unroll
    for (int o = 0; o < 16; ++o) {
        float acc = b2[o];
#pragma unroll
        for (int ii = 0; ii < 32; ++ii) acc = fmaf(h1[ii], W2[o*32+ii], acc);
        h2[o] = acc;
    }
    float po[6];
#pragma unroll
    for (int o = 0; o < 6; ++o) {
        float acc = b3[o];
#pragma unroll
        for (int ii = 0; ii < 16; ++ii) acc = fmaf(h2[ii], W3[o*16+ii], acc);
        po[o] = acc;
    }
    po[0] += px; po[1] += py; po[2] += pz;   // residual on first 3 channels

    float* op = out + (size_t)t * 6;
#pragma unroll
    for (int o = 0; o < 6; ++o) op[o] = po[o];
}

extern "C" void kernel_launch(void* const* d_in, const int* in_sizes, int n_in,
                              void* d_out, int out_size, void* d_ws, size_t ws_size,
                              hipStream_t stream) {
    const float* pos   = (const float*)d_in[0];
    const float* vel   = (const float*)d_in[1];
    const float* initc = (const float*)d_in[2];
    const float* W1    = (const float*)d_in[3];
    const float* b1    = (const float*)d_in[4];
    const float* W2    = (const float*)d_in[5];
    const float* b2    = (const float*)d_in[6];
    const float* W3    = (const float*)d_in[7];
    const float* b3    = (const float*)d_in[8];
    float* out = (float*)d_out;
    int*   nn  = (int*)d_ws;   // 16384 * 12 ints = 768 KB

    knn_kernel<<<dim3(BATCH * (NPTS / QPB)), dim3(256), 0, stream>>>(pos, nn);
    mlp_kernel<<<dim3(BATCH * NPTS / 256), dim3(256), 0, stream>>>(
        pos, vel, initc, W1, b1, W2, b2, W3, b3, nn, out);
}

// Round 5
// 226.277 us; speedup vs baseline: 1.3857x; 1.3857x over previous
//
#include <hip/hip_runtime.h>
#include <stdint.h>

#define BATCH 4
#define NPTS 4096
#define KNN 11            // K+1 neighbors including self
#define LPQ 16            // lanes per query
#define QPB 16            // queries per block (256 threads / 16 lanes)
#define CHUNK 2048        // LDS candidate chunk (32.25 KB with skew)
#define NCHUNK (NPTS / CHUNK)     // 2
#define CPL (CHUNK / LPQ)         // 128 candidates per lane per chunk

// monotone float -> uint mapping (ascending): neg flips all bits, pos sets sign bit
__device__ __forceinline__ unsigned sortable_f32(float d) {
    unsigned b = __float_as_uint(d);
    unsigned m = (unsigned)(((int)b) >> 31) | 0x80000000u;
    return b ^ m;
}

__device__ __forceinline__ unsigned long long shfl_xor_u64_w16(unsigned long long v, int mask) {
    unsigned lo = (unsigned)__shfl_xor((int)(unsigned)(v & 0xFFFFFFFFull), mask, LPQ);
    unsigned hi = (unsigned)__shfl_xor((int)(unsigned)(v >> 32), mask, LPQ);
    return ((unsigned long long)hi << 32) | lo;
}

// branchless insert-if-below-max into sorted-ascending 11-list (evicts max).
// replace last with min(key, last), then one adjacent compare-swap bubble pass.
__device__ __forceinline__ void insert1(unsigned long long (&kd)[KNN],
                                        unsigned long long key) {
    kd[KNN-1] = key < kd[KNN-1] ? key : kd[KNN-1];
#pragma unroll
    for (int k = KNN-1; k > 0; --k) {
        bool sw = kd[k] < kd[k-1];
        unsigned long long lo = sw ? kd[k]   : kd[k-1];
        unsigned long long hi = sw ? kd[k-1] : kd[k];
        kd[k-1] = lo; kd[k] = hi;
    }
}

// Kernel 1: exact 11-NN per point. FROZEN arithmetic (verified r4, passes):
//   sq_j = fl(fl(x2)+fl(y2)) + fl(z2)         (elementwise square, seq sum, no fma)
//   dot  = fma(z,z', fma(y,y', fl(x*x')))     (forward FMA chain)
//   d2   = fl( fl(sq_i+sq_j) - fl(2*dot) )    (no contraction)
// top-k: ascending d2, ties -> LOWER index.
// Key = (sortable_f32(d2) << 32) | j : u64 asc == (d2 asc, j asc on ties).
__global__ __launch_bounds__(256, 4) void knn_kernel(
    const float* __restrict__ pos, int* __restrict__ nn_out)
{
#pragma clang fp contract(off)
    // skewed float4 (x,y,z,sq): idx + (idx>>7) -> 16 partition streams start
    // on distinct bank quads (128*16B stride would alias)
    __shared__ float4 sp[CHUNK + LPQ];

    int b    = blockIdx.x / (NPTS / QPB);   // 256 blocks per batch
    int qblk = blockIdx.x % (NPTS / QPB);
    const float* pb = pos + (size_t)b * NPTS * 3;

    int q = threadIdx.x >> 4;   // query within block (0..15)
    int p = threadIdx.x & 15;   // partition lane (0..15)
    int i = qblk * QPB + q;     // query index within batch

    // query coords from global (L2-hot, 192 KB total). sqq computed EXACTLY
    // like the staged sq (plain mult + seq add) so self-distance bits match r4.
    float xq = pb[3*i], yq = pb[3*i+1], zq = pb[3*i+2];
    float sqq = xq*xq + yq*yq + zq*zq;

    unsigned long long kd[KNN];
#pragma unroll
    for (int k = 0; k < KNN; ++k) kd[k] = 0xFFFFFFFFFFFFFFFFull;

    for (int c = 0; c < NCHUNK; ++c) {
        if (c) __syncthreads();             // protect previous chunk's readers
        for (int j = threadIdx.x; j < CHUNK; j += 256) {
            int g = c * CHUNK + j;
            float x = pb[3*g], y = pb[3*g+1], z = pb[3*g+2];
            float sq = x*x + y*y + z*z;     // contract(off): np sum order
            sp[j + (j >> 7)] = make_float4(x, y, z, sq);
        }
        __syncthreads();

        int sbase = p * (CPL + 1);          // skewed base of this partition
        int jg    = c * CHUNK + p * CPL;    // global index of first candidate
        for (int jl = 0; jl < CPL; jl += 2) {
            float4 c0 = sp[sbase + jl];
            float4 c1 = sp[sbase + jl + 1];

            float t0 = xq * c0.x;            // fl(x*x') == fma(x,x',0)
            t0 = fmaf(yq, c0.y, t0);
            t0 = fmaf(zq, c0.z, t0);
            float d0 = (sqq + c0.w) - 2.0f * t0;

            float t1 = xq * c1.x;
            t1 = fmaf(yq, c1.y, t1);
            t1 = fmaf(zq, c1.z, t1);
            float d1 = (sqq + c1.w) - 2.0f * t1;

            unsigned long long k0 =
                ((unsigned long long)sortable_f32(d0) << 32)
                | (unsigned long long)(unsigned)(jg + jl);
            unsigned long long k1 =
                ((unsigned long long)sortable_f32(d1) << 32)
                | (unsigned long long)(unsigned)(jg + jl + 1);

            // order-independent: result is 11 smallest of union; keys unique
            bool sw = k1 < k0;
            unsigned long long mkey = sw ? k1 : k0;
            unsigned long long Mkey = sw ? k0 : k1;
            insert1(kd, mkey);               // common path, branchless
            if (__ballot(Mkey < kd[KNN-1]))  // rare wave-wide (~12% of iters)
                insert1(kd, Mkey);
        }
    }

    // merge the 16 sorted lists of each query group (lanes q*16..q*16+15):
    // 11 rounds of group-min over the u64 keys (tie-break baked into key)
    unsigned res[KNN];
#pragma unroll
    for (int r = 0; r < KNN; ++r) {
        unsigned long long h = kd[0], o;
        o = shfl_xor_u64_w16(h, 1); if (o < h) h = o;
        o = shfl_xor_u64_w16(h, 2); if (o < h) h = o;
        o = shfl_xor_u64_w16(h, 4); if (o < h) h = o;
        o = shfl_xor_u64_w16(h, 8); if (o < h) h = o;
        res[r] = (unsigned)(h & 0xFFFFFFFFull);
        bool own = (kd[0] == h);            // keys unique -> exactly one owner
#pragma unroll
        for (int t = 0; t < KNN-1; ++t) kd[t] = own ? kd[t+1] : kd[t];
        kd[KNN-1] = own ? 0xFFFFFFFFFFFFFFFFull : kd[KNN-1];
    }

    if (p == 0) {
        int* op = nn_out + ((size_t)b * NPTS + (size_t)i) * 12;  // stride 12
#pragma unroll
        for (int r = 0; r < KNN; ++r) op[r] = (int)res[r];
    }
}

// Kernel 2: gather 66 features + 3 unrolled linear layers. One thread per point.
// block=64, grid=256 -> one wave on every CU (was crowding 64 CUs).
__global__ __launch_bounds__(64) void mlp_kernel(
    const float* __restrict__ pos, const float* __restrict__ vel,
    const float* __restrict__ initc,
    const float* __restrict__ W1, const float* __restrict__ b1,
    const float* __restrict__ W2, const float* __restrict__ b2,
    const float* __restrict__ W3, const float* __restrict__ b3,
    const int* __restrict__ nn, float* __restrict__ out)
{
    int t = blockIdx.x * 64 + threadIdx.x;   // 0..16383
    int b = t >> 12;
    int i = t & (NPTS - 1);

    const int* my_nn = nn + (size_t)t * 12;
    int idx[KNN];
#pragma unroll
    for (int k = 0; k < KNN; ++k) idx[k] = my_nn[k];

    const float* pb = pos + (size_t)b * NPTS * 3;
    const float* vb = vel + (size_t)b * NPTS * 3;
    float px = pb[3*i], py = pb[3*i+1], pz = pb[3*i+2];

    float f[66];
#pragma unroll
    for (int k = 1; k < KNN; ++k) {          // relative positions, ranks 1..10
        const float* pn = pb + 3*idx[k];
        f[3*(k-1)+0] = pn[0] - px;
        f[3*(k-1)+1] = pn[1] - py;
        f[3*(k-1)+2] = pn[2] - pz;
    }
#pragma unroll
    for (int k = 0; k < KNN; ++k) {          // velocities, ranks 0..10 (incl self)
        const float* vn = vb + 3*idx[k];
        f[30+3*k+0] = vn[0];
        f[30+3*k+1] = vn[1];
        f[30+3*k+2] = vn[2];
    }
    f[63] = initc[b*3+0]; f[64] = initc[b*3+1]; f[65] = initc[b*3+2];

    float h1[32];
#pragma unroll
    for (int o = 0; o < 32; ++o) {
        float acc = b1[o];
#pragma unroll
        for (int ff = 0; ff < 66; ++ff) acc = fmaf(f[ff], W1[o*66+ff], acc);
        h1[o] = acc;
    }
    float h2[16];
#pragma unroll
    for (int o = 0; o < 16; ++o) {
        float acc = b2[o];
#pragma unroll
        for (int ii = 0; ii < 32; ++ii) acc = fmaf(h1[ii], W2[o*32+ii], acc);
        h2[o] = acc;
    }
    float po[6];
#pragma unroll
    for (int o = 0; o < 6; ++o) {
        float acc = b3[o];
#pragma unroll
        for (int ii = 0; ii < 16; ++ii) acc = fmaf(h2[ii], W3[o*16+ii], acc);
        po[o] = acc;
    }
    po[0] += px; po[1] += py; po[2] += pz;   // residual on first 3 channels

    float* op = out + (size_t)t * 6;
#pragma unroll
    for (int o = 0; o < 6; ++o) op[o] = po[o];
}

extern "C" void kernel_launch(void* const* d_in, const int* in_sizes, int n_in,
                              void* d_out, int out_size, void* d_ws, size_t ws_size,
                              hipStream_t stream) {
    const float* pos   = (const float*)d_in[0];
    const float* vel   = (const float*)d_in[1];
    const float* initc = (const float*)d_in[2];
    const float* W1    = (const float*)d_in[3];
    const float* b1    = (const float*)d_in[4];
    const float* W2    = (const float*)d_in[5];
    const float* b2    = (const float*)d_in[6];
    const float* W3    = (const float*)d_in[7];
    const float* b3    = (const float*)d_in[8];
    float* out = (float*)d_out;
    int*   nn  = (int*)d_ws;   // 16384 * 12 ints = 768 KB

    knn_kernel<<<dim3(BATCH * (NPTS / QPB)), dim3(256), 0, stream>>>(pos, nn);
    mlp_kernel<<<dim3(BATCH * NPTS / 64), dim3(64), 0, stream>>>(
        pos, vel, initc, W1, b1, W2, b2, W3, b3, nn, out);
}

// Round 6
// 191.775 us; speedup vs baseline: 1.6350x; 1.1799x over previous
//
#include <hip/hip_runtime.h>
#include <stdint.h>

#define BATCH 4
#define NPTS 4096
#define KNN 11            // K+1 neighbors including self
#define LPQ 16            // lanes per query
#define QPB 16            // queries per block (256 threads / 16 lanes)
#define CHUNK 2048        // LDS candidate chunk (32.25 KB with skew)
#define NCHUNK (NPTS / CHUNK)     // 2
#define CPL (CHUNK / LPQ)         // 128 candidates per lane per chunk

// monotone float -> uint mapping (ascending): neg flips all bits, pos sets sign bit
__device__ __forceinline__ unsigned sortable_f32(float d) {
    unsigned b = __float_as_uint(d);
    unsigned m = (unsigned)(((int)b) >> 31) | 0x80000000u;
    return b ^ m;
}

// Kernel 1: exact 11-NN per point. FROZEN arithmetic (verified r4/r5, passes):
//   sq_j = fl(fl(x2)+fl(y2)) + fl(z2)         (elementwise square, seq sum, no fma)
//   dot  = fma(z,z', fma(y,y', fl(x*x')))     (forward FMA chain)
//   d2   = fl( fl(sq_i+sq_j) - fl(2*dot) )    (no contraction)
// top-k: ascending d2, ties -> LOWER index.
// Selection state is SPLIT 32-bit arrays (bd = sortable d2, bi = index):
// strict-< stable insertion scanning j ascending keeps equal-d2 entries in
// lower-j-first order (same result as the r4/r5 packed-u64 key, fewer VALU ops);
// the cross-lane merge compares (bd,bi) lexicographically.
__global__ __launch_bounds__(256, 4) void knn_kernel(
    const float* __restrict__ pos, int* __restrict__ nn_out)
{
#pragma clang fp contract(off)
    // skewed float4 (x,y,z,sq): idx + (idx>>7) -> 16 partition streams start
    // on distinct bank quads (128*16B stride would alias)
    __shared__ float4 sp[CHUNK + LPQ];

    int b    = blockIdx.x / (NPTS / QPB);   // 256 blocks per batch
    int qblk = blockIdx.x % (NPTS / QPB);
    const float* pb = pos + (size_t)b * NPTS * 3;

    int q = threadIdx.x >> 4;   // query within block (0..15)
    int p = threadIdx.x & 15;   // partition lane (0..15)
    int i = qblk * QPB + q;     // query index within batch

    // query coords from global (L2-hot). sqq computed EXACTLY like staged sq.
    float xq = pb[3*i], yq = pb[3*i+1], zq = pb[3*i+2];
    float sqq = xq*xq + yq*yq + zq*zq;

    unsigned bd[KNN], bi[KNN];
#pragma unroll
    for (int k = 0; k < KNN; ++k) { bd[k] = 0xFFFFFFFFu; bi[k] = 0u; }

    for (int c = 0; c < NCHUNK; ++c) {
        if (c) __syncthreads();             // protect previous chunk's readers
        for (int j = threadIdx.x; j < CHUNK; j += 256) {
            int g = c * CHUNK + j;
            float x = pb[3*g], y = pb[3*g+1], z = pb[3*g+2];
            float sq = x*x + y*y + z*z;     // contract(off): np sum order
            sp[j + (j >> 7)] = make_float4(x, y, z, sq);
        }
        __syncthreads();

        int sbase = p * (CPL + 1);          // skewed base of this partition
        int jg    = c * CHUNK + p * CPL;    // global index of first candidate
#pragma unroll 4
        for (int jl = 0; jl < CPL; ++jl) {
            float4 cc = sp[sbase + jl];
            float t = xq * cc.x;             // fl(x*x') == fma(x,x',0)
            t = fmaf(yq, cc.y, t);           // forward FMA chain
            t = fmaf(zq, cc.z, t);
            float d2 = (sqq + cc.w) - 2.0f * t;  // unfused
            unsigned u = sortable_f32(d2);
            unsigned jj = (unsigned)(jg + jl);
            // branchless stable insert-if-below-max (strict <), evict max
            bool in = u < bd[KNN-1];
            bd[KNN-1] = in ? u : bd[KNN-1];
            bi[KNN-1] = in ? jj : bi[KNN-1];
#pragma unroll
            for (int k = KNN-1; k > 0; --k) {
                bool sw = bd[k] < bd[k-1];   // strict: equal d2 keeps order
                unsigned d_lo = sw ? bd[k]   : bd[k-1];
                unsigned d_hi = sw ? bd[k-1] : bd[k];
                unsigned i_lo = sw ? bi[k]   : bi[k-1];
                unsigned i_hi = sw ? bi[k-1] : bi[k];
                bd[k-1] = d_lo; bd[k] = d_hi;
                bi[k-1] = i_lo; bi[k] = i_hi;
            }
        }
    }

    // merge the 16 sorted lists of each query group: 11 rounds of group-min
    // with lexicographic (bd, bi) compare (ties -> lower index)
    unsigned res[KNN];
#pragma unroll
    for (int r = 0; r < KNN; ++r) {
        unsigned h = bd[0], hi = bi[0];
#pragma unroll
        for (int m = 1; m <= 8; m <<= 1) {
            unsigned od = (unsigned)__shfl_xor((int)h,  m, LPQ);
            unsigned oi = (unsigned)__shfl_xor((int)hi, m, LPQ);
            bool take = (od < h) || (od == h && oi < hi);
            h  = take ? od : h;
            hi = take ? oi : hi;
        }
        res[r] = hi;
        // unique owner: (d2,j) pairs are unique across the group's real entries
        bool own = (bd[0] == h) && (bi[0] == hi);
#pragma unroll
        for (int t = 0; t < KNN-1; ++t) {
            bd[t] = own ? bd[t+1] : bd[t];
            bi[t] = own ? bi[t+1] : bi[t];
        }
        bd[KNN-1] = own ? 0xFFFFFFFFu : bd[KNN-1];  // bi stays (unique per lane)
    }

    if (p == 0) {
        int* op = nn_out + ((size_t)b * NPTS + (size_t)i) * 12;  // stride 12
#pragma unroll
        for (int r = 0; r < KNN; ++r) op[r] = (int)res[r];
    }
}

// Kernel 2: 4 threads per point (65536 threads = 1024 waves = 1/SIMD device-wide;
// the old 1-thread/point layout was 256 waves = 1 wave per 4 SIMDs — structurally
// unable to occupy the chip). Weights staged in LDS (11 KB); thread r of a point
// computes h1[r*8..r*8+7], h2 reduced across the 4 lanes via shfl_xor width 4,
// layer 3 redundant, lane r==0 writes.
__global__ __launch_bounds__(256) void mlp_kernel(
    const float* __restrict__ pos, const float* __restrict__ vel,
    const float* __restrict__ initc,
    const float* __restrict__ W1, const float* __restrict__ b1,
    const float* __restrict__ W2, const float* __restrict__ b2,
    const float* __restrict__ W3, const float* __restrict__ b3,
    const int* __restrict__ nn, float* __restrict__ out)
{
    __shared__ float wls[2112 + 512 + 96 + 32 + 16 + 8];
    float* sW1 = wls;
    float* sW2 = wls + 2112;
    float* sW3 = wls + 2624;
    float* sb1 = wls + 2720;
    float* sb2 = wls + 2752;
    float* sb3 = wls + 2768;

    for (int k = threadIdx.x; k < 2112; k += 256) sW1[k] = W1[k];
    for (int k = threadIdx.x; k < 512;  k += 256) sW2[k] = W2[k];
    if (threadIdx.x < 96) sW3[threadIdx.x] = W3[threadIdx.x];
    if (threadIdx.x < 32) sb1[threadIdx.x] = b1[threadIdx.x];
    if (threadIdx.x < 16) sb2[threadIdx.x] = b2[threadIdx.x];
    if (threadIdx.x < 6)  sb3[threadIdx.x] = b3[threadIdx.x];

    int t4 = blockIdx.x * 256 + threadIdx.x;  // 0..65535
    int pt = t4 >> 2;                         // point 0..16383
    int r  = t4 & 3;                          // h1-slice 0..3
    int b  = pt >> 12;
    int i  = pt & (NPTS - 1);

    const int* my_nn = nn + (size_t)pt * 12;
    int idx[KNN];
#pragma unroll
    for (int k = 0; k < KNN; ++k) idx[k] = my_nn[k];

    const float* pb = pos + (size_t)b * NPTS * 3;
    const float* vb = vel + (size_t)b * NPTS * 3;
    float px = pb[3*i], py = pb[3*i+1], pz = pb[3*i+2];

    float f[66];
#pragma unroll
    for (int k = 1; k < KNN; ++k) {          // relative positions, ranks 1..10
        const float* pn = pb + 3*idx[k];
        f[3*(k-1)+0] = pn[0] - px;
        f[3*(k-1)+1] = pn[1] - py;
        f[3*(k-1)+2] = pn[2] - pz;
    }
#pragma unroll
    for (int k = 0; k < KNN; ++k) {          // velocities, ranks 0..10 (incl self)
        const float* vn = vb + 3*idx[k];
        f[30+3*k+0] = vn[0];
        f[30+3*k+1] = vn[1];
        f[30+3*k+2] = vn[2];
    }
    f[63] = initc[b*3+0]; f[64] = initc[b*3+1]; f[65] = initc[b*3+2];

    __syncthreads();                          // weights staged

    float h1l[8];                             // my 8 of the 32 h1 outputs
#pragma unroll
    for (int o = 0; o < 8; ++o) {
        int og = r * 8 + o;
        float acc = sb1[og];
#pragma unroll
        for (int ff = 0; ff < 66; ++ff) acc = fmaf(f[ff], sW1[og*66+ff], acc);
        h1l[o] = acc;
    }

    float h2[16];
#pragma unroll
    for (int o = 0; o < 16; ++o) {
        float acc = 0.0f;
#pragma unroll
        for (int ii = 0; ii < 8; ++ii)
            acc = fmaf(h1l[ii], sW2[o*32 + r*8 + ii], acc);
        acc += __shfl_xor(acc, 1, 4);         // reduce across the point's 4 lanes
        acc += __shfl_xor(acc, 2, 4);
        h2[o] = acc + sb2[o];
    }

    float po[6];
#pragma unroll
    for (int o = 0; o < 6; ++o) {
        float acc = sb3[o];
#pragma unroll
        for (int ii = 0; ii < 16; ++ii) acc = fmaf(h2[ii], sW3[o*16+ii], acc);
        po[o] = acc;
    }
    po[0] += px; po[1] += py; po[2] += pz;    // residual on first 3 channels

    if (r == 0) {
        float* op = out + (size_t)pt * 6;
#pragma unroll
        for (int o = 0; o < 6; ++o) op[o] = po[o];
    }
}

extern "C" void kernel_launch(void* const* d_in, const int* in_sizes, int n_in,
                              void* d_out, int out_size, void* d_ws, size_t ws_size,
                              hipStream_t stream) {
    const float* pos   = (const float*)d_in[0];
    const float* vel   = (const float*)d_in[1];
    const float* initc = (const float*)d_in[2];
    const float* W1    = (const float*)d_in[3];
    const float* b1    = (const float*)d_in[4];
    const float* W2    = (const float*)d_in[5];
    const float* b2    = (const float*)d_in[6];
    const float* W3    = (const float*)d_in[7];
    const float* b3    = (const float*)d_in[8];
    float* out = (float*)d_out;
    int*   nn  = (int*)d_ws;   // 16384 * 12 ints = 768 KB

    knn_kernel<<<dim3(BATCH * (NPTS / QPB)), dim3(256), 0, stream>>>(pos, nn);
    mlp_kernel<<<dim3(BATCH * NPTS * 4 / 256), dim3(256), 0, stream>>>(
        pos, vel, initc, W1, b1, W2, b2, W3, b3, nn, out);
}

// Round 7
// 190.566 us; speedup vs baseline: 1.6454x; 1.0063x over previous
//
#include <hip/hip_runtime.h>
#include <stdint.h>

#define BATCH 4
#define NPTS 4096
#define KNN 11            // K+1 neighbors including self
#define LPQ 16            // lanes per query
#define QPB 16            // queries per block (256 threads / 16 lanes)
#define CHUNK 2048        // LDS candidate chunk (32.25 KB with skew)
#define NCHUNK (NPTS / CHUNK)     // 2
#define CPL (CHUNK / LPQ)         // 128 candidates per lane per chunk

// monotone float -> uint mapping (ascending): neg flips all bits, pos sets sign bit
__device__ __forceinline__ unsigned sortable_f32(float d) {
    unsigned b = __float_as_uint(d);
    unsigned m = (unsigned)(((int)b) >> 31) | 0x80000000u;
    return b ^ m;
}

// Fused: exact 11-NN (FROZEN arithmetic, verified r4-r6) + 66->32->16->6 MLP.
//   sq_j = fl(fl(x2)+fl(y2)) + fl(z2)         (elementwise square, seq sum, no fma)
//   dot  = fma(z,z', fma(y,y', fl(x*x')))     (forward FMA chain)
//   d2   = fl( fl(sq_i+sq_j) - fl(2*dot) )    (no contraction)
// top-k: ascending d2, ties -> LOWER index.
// Selection: phase 1 = per-lane 11-smallest VALUES via min/max (med3) network
// (cheap); tau = exact query-wide 11th value via 16-lane k-way merge; phase 2 =
// rescan with (u<=tau) gate (wave-any ~16%) doing the full stable (u,j) insert
// only when some lane qualifies. Per-lane cap 11 is safe: the true top-11
// members from a lane are always among that lane's 11 lex-smallest qualifiers.
__global__ __launch_bounds__(256, 4) void fused_kernel(
    const float* __restrict__ pos, const float* __restrict__ vel,
    const float* __restrict__ initc,
    const float* __restrict__ W1, const float* __restrict__ b1,
    const float* __restrict__ W2, const float* __restrict__ b2,
    const float* __restrict__ W3, const float* __restrict__ b3,
    float* __restrict__ out)
{
#pragma clang fp contract(off)
    // skewed float4 (x,y,z,sq): idx + (idx>>7) -> 16 partition streams start
    // on distinct bank quads (128*16B stride would alias)
    __shared__ float4 sp[CHUNK + LPQ];

    int b    = blockIdx.x / (NPTS / QPB);   // 256 blocks per batch
    int qblk = blockIdx.x % (NPTS / QPB);
    const float* pb = pos + (size_t)b * NPTS * 3;

    int q = threadIdx.x >> 4;   // query within block (0..15)
    int p = threadIdx.x & 15;   // partition lane (0..15)
    int i = qblk * QPB + q;     // query index within batch

    float xq = pb[3*i], yq = pb[3*i+1], zq = pb[3*i+2];
    float sqq = xq*xq + yq*yq + zq*zq;      // contract(off): np sum order

    // ---------------- phase 1: per-lane 11 smallest d2 VALUES ----------------
    unsigned vd[KNN];
#pragma unroll
    for (int k = 0; k < KNN; ++k) vd[k] = 0xFFFFFFFFu;

    for (int c = 0; c < NCHUNK; ++c) {
        if (c) __syncthreads();
        for (int j = threadIdx.x; j < CHUNK; j += 256) {
            int g = c * CHUNK + j;
            float x = pb[3*g], y = pb[3*g+1], z = pb[3*g+2];
            float sq = x*x + y*y + z*z;     // contract(off)
            sp[j + (j >> 7)] = make_float4(x, y, z, sq);
        }
        __syncthreads();

        int sbase = p * (CPL + 1);
#pragma unroll 4
        for (int jl = 0; jl < CPL; ++jl) {
            float4 cc = sp[sbase + jl];
            float t = xq * cc.x;             // FROZEN d2 arithmetic
            t = fmaf(yq, cc.y, t);
            t = fmaf(zq, cc.z, t);
            float d2 = (sqq + cc.w) - 2.0f * t;
            unsigned u = sortable_f32(d2);
            // sorted insert-and-evict-max, values only:
            // new[k] = max(old[k-1], min(old[k], u)) descending k; new[0]=min.
#pragma unroll
            for (int k = KNN-1; k > 0; --k) {
                unsigned mn = vd[k] < u ? vd[k] : u;
                vd[k] = vd[k-1] > mn ? vd[k-1] : mn;   // med3 pattern
            }
            vd[0] = vd[0] < u ? vd[0] : u;
        }
    }

    // -------- tau: exact 11th-smallest value of the query's 4096 d2's --------
    // 11-round k-way merge over the 16 per-lane sorted value lists;
    // (value, lane) lex order -> exactly one owner pops per round.
    unsigned tau = 0xFFFFFFFFu;
#pragma unroll
    for (int r = 0; r < KNN; ++r) {
        unsigned h = vd[0], hl = (unsigned)p;
#pragma unroll
        for (int m = 1; m <= 8; m <<= 1) {
            unsigned oh = (unsigned)__shfl_xor((int)h,  m, LPQ);
            unsigned ol = (unsigned)__shfl_xor((int)hl, m, LPQ);
            bool take = (oh < h) || (oh == h && ol < hl);
            h  = take ? oh : h;
            hl = take ? ol : hl;
        }
        tau = h;                             // final round leaves the 11th
        bool own = (hl == (unsigned)p);
#pragma unroll
        for (int t = 0; t < KNN-1; ++t) vd[t] = own ? vd[t+1] : vd[t];
        vd[KNN-1] = own ? 0xFFFFFFFFu : vd[KNN-1];
    }

    // ---------------- phase 2: rescan, collect (u,j) with u <= tau ----------
    unsigned bd[KNN], bi[KNN];
#pragma unroll
    for (int k = 0; k < KNN; ++k) { bd[k] = 0xFFFFFFFFu; bi[k] = 0u; }

    for (int c = 0; c < NCHUNK; ++c) {
        __syncthreads();                     // protect previous chunk readers
        for (int j = threadIdx.x; j < CHUNK; j += 256) {
            int g = c * CHUNK + j;
            float x = pb[3*g], y = pb[3*g+1], z = pb[3*g+2];
            float sq = x*x + y*y + z*z;      // identical bits to phase-1 stage
            sp[j + (j >> 7)] = make_float4(x, y, z, sq);
        }
        __syncthreads();

        int sbase = p * (CPL + 1);
        int jg    = c * CHUNK + p * CPL;
#pragma unroll 4
        for (int jl = 0; jl < CPL; ++jl) {
            float4 cc = sp[sbase + jl];
            float t = xq * cc.x;             // FROZEN d2 arithmetic (same bits)
            t = fmaf(yq, cc.y, t);
            t = fmaf(zq, cc.z, t);
            float d2 = (sqq + cc.w) - 2.0f * t;
            unsigned u = sortable_f32(d2);
            bool in = (u <= tau) && (u < bd[KNN-1]);
            if (__ballot(in)) {              // ~16% of iterations wave-wide
                unsigned jj = (unsigned)(jg + jl);
                bd[KNN-1] = in ? u  : bd[KNN-1];
                bi[KNN-1] = in ? jj : bi[KNN-1];
#pragma unroll
                for (int k = KNN-1; k > 0; --k) {
                    bool sw = bd[k] < bd[k-1];   // strict: equal d2 keeps order
                    unsigned d_lo = sw ? bd[k]   : bd[k-1];
                    unsigned d_hi = sw ? bd[k-1] : bd[k];
                    unsigned i_lo = sw ? bi[k]   : bi[k-1];
                    unsigned i_hi = sw ? bi[k-1] : bi[k];
                    bd[k-1] = d_lo; bd[k] = d_hi;
                    bi[k-1] = i_lo; bi[k] = i_hi;
                }
            }
        }
    }

    // -------- final merge (r6-verbatim): 11 rounds of lex group-min ---------
    // Sentinels (0xFFFFFFFF) are lex-largest and real entries >= 11, so no
    // sentinel is ever popped; real (u,j) are unique -> exactly one owner.
    unsigned res[KNN];
#pragma unroll
    for (int r = 0; r < KNN; ++r) {
        unsigned h = bd[0], hi = bi[0];
#pragma unroll
        for (int m = 1; m <= 8; m <<= 1) {
            unsigned od = (unsigned)__shfl_xor((int)h,  m, LPQ);
            unsigned oi = (unsigned)__shfl_xor((int)hi, m, LPQ);
            bool take = (od < h) || (od == h && oi < hi);
            h  = take ? od : h;
            hi = take ? oi : hi;
        }
        res[r] = hi;
        bool own = (bd[0] == h) && (bi[0] == hi);
#pragma unroll
        for (int t = 0; t < KNN-1; ++t) {
            bd[t] = own ? bd[t+1] : bd[t];
            bi[t] = own ? bi[t+1] : bi[t];
        }
        bd[KNN-1] = own ? 0xFFFFFFFFu : bd[KNN-1];
    }

    // ---------------- fused MLP epilogue (r4-verbatim arithmetic) -----------
    // all 16 lanes hold identical res[]; lane p==0 runs the MLP for query i.
    // Weight indices are uniform across active lanes -> scalar loads.
    if (p == 0) {
        const float* vb = vel + (size_t)b * NPTS * 3;
        float px = xq, py = yq, pz = zq;

        float f[66];
#pragma unroll
        for (int k = 1; k < KNN; ++k) {      // relative positions, ranks 1..10
            const float* pn = pb + 3*(int)res[k];
            f[3*(k-1)+0] = pn[0] - px;
            f[3*(k-1)+1] = pn[1] - py;
            f[3*(k-1)+2] = pn[2] - pz;
        }
#pragma unroll
        for (int k = 0; k < KNN; ++k) {      // velocities, ranks 0..10
            const float* vn = vb + 3*(int)res[k];
            f[30+3*k+0] = vn[0];
            f[30+3*k+1] = vn[1];
            f[30+3*k+2] = vn[2];
        }
        f[63] = initc[b*3+0]; f[64] = initc[b*3+1]; f[65] = initc[b*3+2];

        float h1[32];
#pragma unroll
        for (int o = 0; o < 32; ++o) {
            float acc = b1[o];
#pragma unroll
            for (int ff = 0; ff < 66; ++ff) acc = fmaf(f[ff], W1[o*66+ff], acc);
            h1[o] = acc;
        }
        float h2[16];
#pragma unroll
        for (int o = 0; o < 16; ++o) {
            float acc = b2[o];
#pragma unroll
            for (int ii = 0; ii < 32; ++ii) acc = fmaf(h1[ii], W2[o*32+ii], acc);
            h2[o] = acc;
        }
        float po[6];
#pragma unroll
        for (int o = 0; o < 6; ++o) {
            float acc = b3[o];
#pragma unroll
            for (int ii = 0; ii < 16; ++ii) acc = fmaf(h2[ii], W3[o*16+ii], acc);
            po[o] = acc;
        }
        po[0] += px; po[1] += py; po[2] += pz;   // residual on first 3 channels

        float* op = out + ((size_t)b * NPTS + (size_t)i) * 6;
#pragma unroll
        for (int o = 0; o < 6; ++o) op[o] = po[o];
    }
}

extern "C" void kernel_launch(void* const* d_in, const int* in_sizes, int n_in,
                              void* d_out, int out_size, void* d_ws, size_t ws_size,
                              hipStream_t stream) {
    const float* pos   = (const float*)d_in[0];
    const float* vel   = (const float*)d_in[1];
    const float* initc = (const float*)d_in[2];
    const float* W1    = (const float*)d_in[3];
    const float* b1    = (const float*)d_in[4];
    const float* W2    = (const float*)d_in[5];
    const float* b2    = (const float*)d_in[6];
    const float* W3    = (const float*)d_in[7];
    const float* b3    = (const float*)d_in[8];
    float* out = (float*)d_out;

    fused_kernel<<<dim3(BATCH * (NPTS / QPB)), dim3(256), 0, stream>>>(
        pos, vel, initc, W1, b1, W2, b2, W3, b3, out);
}

// Round 8
// 143.660 us; speedup vs baseline: 2.1826x; 1.3265x over previous
//
#include <hip/hip_runtime.h>
#include <stdint.h>

#define BATCH 4
#define NPTS 4096
#define KNN 11            // K+1 neighbors including self
#define LPQ 16            // lanes per query
#define QPB 16            // queries per block (256 threads / 16 lanes)
#define CHUNK 2048        // LDS candidate chunk (32.25 KB with skew)
#define NCHUNK (NPTS / CHUNK)     // 2
#define CPL (CHUNK / LPQ)         // 128 candidates per lane per chunk

#define SENTINEL_BITS 0x433FFFFFFFFFFFFFll   // exp 0x433, mantissa all-ones

// monotone float -> uint mapping (ascending): neg flips all bits, pos sets sign bit
__device__ __forceinline__ unsigned sortable_f32(float d) {
    unsigned b = __float_as_uint(d);
    unsigned m = (unsigned)(((int)b) >> 31) | 0x80000000u;
    return b ^ m;
}

// Fused exact 11-NN + 66->32->16->6 MLP. FROZEN d2 arithmetic (verified r4-r7):
//   sq_j = fl(fl(x2)+fl(y2)) + fl(z2)         (elementwise square, seq sum, no fma)
//   dot  = fma(z,z', fma(y,y', fl(x*x')))     (forward FMA chain)
//   d2   = fl( fl(sq_i+sq_j) - fl(2*dot) )    (no contraction)
// top-k: ascending d2, ties -> LOWER index.
// Selection: keys are doubles with bit pattern 0x433<<52 | sortable(d2)<<12 | j.
// Same sign+exponent => f64 ordering == 44-bit key ordering == (d2 asc, j asc):
// the tie-break is baked into the value, so a cheap VALUES-ONLY min/max insert
// network (2 f64 ops/stage) replaces the (value,index)-pair swap network.
__global__ __launch_bounds__(256, 4) void fused_kernel(
    const float* __restrict__ pos, const float* __restrict__ vel,
    const float* __restrict__ initc,
    const float* __restrict__ W1, const float* __restrict__ b1,
    const float* __restrict__ W2, const float* __restrict__ b2,
    const float* __restrict__ W3, const float* __restrict__ b3,
    float* __restrict__ out)
{
#pragma clang fp contract(off)
    // skewed float4 (x,y,z,sq): idx + (idx>>7) -> 16 partition streams start
    // on distinct bank quads (128*16B stride would alias)
    __shared__ float4 sp[CHUNK + LPQ];

    int b    = blockIdx.x / (NPTS / QPB);   // 256 blocks per batch
    int qblk = blockIdx.x % (NPTS / QPB);
    const float* pb = pos + (size_t)b * NPTS * 3;

    int q = threadIdx.x >> 4;   // query within block (0..15)
    int p = threadIdx.x & 15;   // partition lane (0..15)
    int i = qblk * QPB + q;     // query index within batch

    float xq = pb[3*i], yq = pb[3*i+1], zq = pb[3*i+2];
    float sqq = xq*xq + yq*yq + zq*zq;      // contract(off): np sum order

    double kd[KNN];
#pragma unroll
    for (int k = 0; k < KNN; ++k) kd[k] = __longlong_as_double(SENTINEL_BITS);

    for (int c = 0; c < NCHUNK; ++c) {
        if (c) __syncthreads();
        for (int j = threadIdx.x; j < CHUNK; j += 256) {
            int g = c * CHUNK + j;
            float x = pb[3*g], y = pb[3*g+1], z = pb[3*g+2];
            float sq = x*x + y*y + z*z;     // contract(off)
            sp[j + (j >> 7)] = make_float4(x, y, z, sq);
        }
        __syncthreads();

        int sbase = p * (CPL + 1);
        int jg    = c * CHUNK + p * CPL;
#pragma unroll 4
        for (int jl = 0; jl < CPL; ++jl) {
            float4 cc = sp[sbase + jl];
            float t = xq * cc.x;             // FROZEN d2 arithmetic
            t = fmaf(yq, cc.y, t);
            t = fmaf(zq, cc.z, t);
            float d2 = (sqq + cc.w) - 2.0f * t;
            unsigned u = sortable_f32(d2);
            unsigned jj = (unsigned)(jg + jl);
            // pack: exp 0x433 | u<<12 | j  (44-bit payload in the mantissa)
            unsigned lo = (u << 12) | jj;
            unsigned hi = 0x43300000u | (u >> 20);
            double key = __longlong_as_double(
                ((long long)(int)hi << 32) | (unsigned long long)lo);
            // sorted insert-and-evict-max, values only (2 f64 ops per stage)
#pragma unroll
            for (int k = KNN-1; k > 0; --k) {
                double mn = fmin(kd[k], key);
                kd[k] = fmax(kd[k-1], mn);
            }
            kd[0] = fmin(kd[0], key);
        }
    }

    // merge the 16 per-lane sorted lists: 11 rounds of group-min (f64 min);
    // keys unique (j distinct) -> exactly one owner pops per round.
    unsigned res[KNN];
#pragma unroll
    for (int r = 0; r < KNN; ++r) {
        double h = kd[0];
#pragma unroll
        for (int m = 1; m <= 8; m <<= 1)
            h = fmin(h, __shfl_xor(h, m, LPQ));
        long long hb = __double_as_longlong(h);
        res[r] = (unsigned)(hb & 0xFFF);
        bool own = (__double_as_longlong(kd[0]) == hb);
#pragma unroll
        for (int t = 0; t < KNN-1; ++t) kd[t] = own ? kd[t+1] : kd[t];
        kd[KNN-1] = own ? __longlong_as_double(SENTINEL_BITS) : kd[KNN-1];
    }

    // ---------- fused MLP, lane-parallel, BIT-IDENTICAL to r4 ----------
    // lane p computes h1 rows {2p,2p+1} (features accumulated on the fly in
    // ff order 0..65), h2 row p via 32 ordered shfl broadcasts, layer-3 row
    // min(p,5) redundantly; lanes p<6 store. All accumulation orders match
    // the r4 sequential version exactly.
    const float* vb = vel + (size_t)b * NPTS * 3;

    const float* w0 = W1 + (2*p)   * 66;
    const float* w1 = W1 + (2*p+1) * 66;
    float a0 = b1[2*p], a1 = b1[2*p+1];
#pragma unroll
    for (int k = 1; k < KNN; ++k) {          // ff = 0..29: relative positions
        const float* pn = pb + 3*(int)res[k];
        float dx = pn[0] - xq, dy = pn[1] - yq, dz = pn[2] - zq;
        int ff = 3*(k-1);
        a0 = fmaf(dx, w0[ff+0], a0); a1 = fmaf(dx, w1[ff+0], a1);
        a0 = fmaf(dy, w0[ff+1], a0); a1 = fmaf(dy, w1[ff+1], a1);
        a0 = fmaf(dz, w0[ff+2], a0); a1 = fmaf(dz, w1[ff+2], a1);
    }
#pragma unroll
    for (int k = 0; k < KNN; ++k) {          // ff = 30..62: velocities
        const float* vn = vb + 3*(int)res[k];
        int ff = 30 + 3*k;
        a0 = fmaf(vn[0], w0[ff+0], a0); a1 = fmaf(vn[0], w1[ff+0], a1);
        a0 = fmaf(vn[1], w0[ff+1], a0); a1 = fmaf(vn[1], w1[ff+1], a1);
        a0 = fmaf(vn[2], w0[ff+2], a0); a1 = fmaf(vn[2], w1[ff+2], a1);
    }
    float c0 = initc[b*3+0], c1 = initc[b*3+1], c2 = initc[b*3+2];
    a0 = fmaf(c0, w0[63], a0); a1 = fmaf(c0, w1[63], a1);
    a0 = fmaf(c1, w0[64], a0); a1 = fmaf(c1, w1[64], a1);
    a0 = fmaf(c2, w0[65], a0); a1 = fmaf(c2, w1[65], a1);

    // h2 row p: acc = b2[p] + sum_{ii=0..31} h1[ii]*W2[p*32+ii]  (ordered)
    float h2 = b2[p];
    const float* w2 = W2 + p * 32;
#pragma unroll
    for (int ii = 0; ii < 32; ++ii) {
        float h1v = __shfl((ii & 1) ? a1 : a0, ii >> 1, LPQ);
        h2 = fmaf(h1v, w2[ii], h2);
    }

    // layer 3 row min(p,5): acc = b3[o] + sum_{ii=0..15} h2[ii]*W3[o*16+ii]
    int o3 = p < 6 ? p : 0;
    float po = b3[o3];
    const float* w3 = W3 + o3 * 16;
#pragma unroll
    for (int ii = 0; ii < 16; ++ii) {
        float h2v = __shfl(h2, ii, LPQ);
        po = fmaf(h2v, w3[ii], po);
    }
    float resid = (p == 0) ? xq : (p == 1) ? yq : (p == 2) ? zq : 0.0f;
    po += resid;                              // residual on first 3 channels

    if (p < 6)
        out[((size_t)b * NPTS + (size_t)i) * 6 + p] = po;
}

extern "C" void kernel_launch(void* const* d_in, const int* in_sizes, int n_in,
                              void* d_out, int out_size, void* d_ws, size_t ws_size,
                              hipStream_t stream) {
    const float* pos   = (const float*)d_in[0];
    const float* vel   = (const float*)d_in[1];
    const float* initc = (const float*)d_in[2];
    const float* W1    = (const float*)d_in[3];
    const float* b1    = (const float*)d_in[4];
    const float* W2    = (const float*)d_in[5];
    const float* b2    = (const float*)d_in[6];
    const float* W3    = (const float*)d_in[7];
    const float* b3    = (const float*)d_in[8];
    float* out = (float*)d_out;

    fused_kernel<<<dim3(BATCH * (NPTS / QPB)), dim3(256), 0, stream>>>(
        pos, vel, initc, W1, b1, W2, b2, W3, b3, out);
}